// Round 2
// baseline (620.144 us; speedup 1.0000x reference)
//
#include <hip/hip_runtime.h>
#include <hip/hip_bf16.h>
#include <cmath>

#define BS 8
#define SEQ 16384
#define D 128
#define NH 8
#define HD 16
#define EPS_ 1e-5f

#define TOK 32                      // tokens per LDS chunk
#define CHB 64                      // blocks per batch
#define TPB_TOKENS (SEQ / CHB)      // 256 tokens per block
#define NCHUNK (TPB_TOKENS / TOK)   // 8 chunks per block

#define KV_ELEMS (BS * NH * HD * HD)   // 16384 floats
#define KSUM_ELEMS (BS * NH * HD)      // 1024 floats

// ---------------------------------------------------------------------------
// Pass A: k = Q@Wk + bk, v = Q@Wv + bv, phi_k = elu(k)+1;
//         KV[b,h,d,m] += phi_k[l,h,d] * v[l,h,m];  Ksum[b,h,d] += phi_k[l,h,d]
// ---------------------------------------------------------------------------
__global__ __launch_bounds__(256) void kv_accum_kernel(
    const float* __restrict__ Q,
    const float* __restrict__ Wk, const float* __restrict__ bk,
    const float* __restrict__ Wv, const float* __restrict__ bv,
    float* __restrict__ KV, float* __restrict__ Ksum)
{
    __shared__ float Qs[TOK][D];   // 16 KB
    __shared__ float pk[TOK][D];   // 16 KB
    __shared__ float vs[TOK][D];   // 16 KB

    const int b  = blockIdx.x / CHB;
    const int cb = blockIdx.x % CHB;
    const int t  = threadIdx.x;
    const int c  = t & 127;        // output column (0..127)
    const int tg = t >> 7;         // token group (0..1), 16 tokens each

    const float bkc = bk[c];
    const float bvc = bv[c];

    // KV accumulation ownership: h = t>>5 (0..7), idx = t&31; each thread owns
    // 8 consecutive (d,m) slots dm = idx*8 + r.  For r in [0,8): d = idx>>1
    // (constant per thread), m = (idx&1)*8 + r.
    const int h   = t >> 5;
    const int idx = t & 31;
    const int d0  = idx >> 1;
    const int m0  = (idx & 1) * 8;

    float kvacc[8];
#pragma unroll
    for (int r = 0; r < 8; ++r) kvacc[r] = 0.f;
    float ksacc = 0.f;             // valid for t < 128: (h2 = t>>4, d2 = t&15)

    for (int ch = 0; ch < NCHUNK; ++ch) {
        const long tok0 = (long)b * SEQ + (long)cb * TPB_TOKENS + (long)ch * TOK;

        __syncthreads();  // protect Qs/pk/vs from previous chunk's readers
        {
            const float4* Qg  = (const float4*)(Q + tok0 * D);
            float4*       Qs4 = (float4*)&Qs[0][0];
            for (int i = t; i < TOK * D / 4; i += 256) Qs4[i] = Qg[i];
        }
        __syncthreads();

        // --- k and v projections (register-blocked over 16 tokens) ---
        float acck[16], accv[16];
#pragma unroll
        for (int tt = 0; tt < 16; ++tt) { acck[tt] = bkc; accv[tt] = bvc; }

        for (int kk = 0; kk < D; kk += 4) {
            const float wk0 = Wk[(kk + 0) * D + c];
            const float wk1 = Wk[(kk + 1) * D + c];
            const float wk2 = Wk[(kk + 2) * D + c];
            const float wk3 = Wk[(kk + 3) * D + c];
            const float wv0 = Wv[(kk + 0) * D + c];
            const float wv1 = Wv[(kk + 1) * D + c];
            const float wv2 = Wv[(kk + 2) * D + c];
            const float wv3 = Wv[(kk + 3) * D + c];
#pragma unroll
            for (int tt = 0; tt < 16; ++tt) {
                const float4 q4 = *(const float4*)&Qs[tg * 16 + tt][kk];
                acck[tt] += q4.x * wk0 + q4.y * wk1 + q4.z * wk2 + q4.w * wk3;
                accv[tt] += q4.x * wv0 + q4.y * wv1 + q4.z * wv2 + q4.w * wv3;
            }
        }

        // phi_k = elu(k)+1 = (k>0 ? k+1 : exp(k))
#pragma unroll
        for (int tt = 0; tt < 16; ++tt) {
            const float x = acck[tt];
            pk[tg * 16 + tt][c] = (x > 0.f) ? (x + 1.f) : __expf(x);
            vs[tg * 16 + tt][c] = accv[tt];
        }
        __syncthreads();

        // --- KV and Ksum accumulation for this chunk ---
#pragma unroll
        for (int tok = 0; tok < TOK; ++tok) {
            const float  pkd = pk[tok][h * HD + d0];
            const float4 v0  = *(const float4*)&vs[tok][h * HD + m0];
            const float4 v1  = *(const float4*)&vs[tok][h * HD + m0 + 4];
            kvacc[0] += pkd * v0.x;
            kvacc[1] += pkd * v0.y;
            kvacc[2] += pkd * v0.z;
            kvacc[3] += pkd * v0.w;
            kvacc[4] += pkd * v1.x;
            kvacc[5] += pkd * v1.y;
            kvacc[6] += pkd * v1.z;
            kvacc[7] += pkd * v1.w;
        }
        if (t < 128) {
#pragma unroll
            for (int tok = 0; tok < TOK; ++tok)
                ksacc += pk[tok][(t >> 4) * HD + (t & 15)];
        }
    }

#pragma unroll
    for (int r = 0; r < 8; ++r)
        atomicAdd(&KV[(b * NH + h) * HD * HD + idx * 8 + r], kvacc[r]);
    if (t < 128)
        atomicAdd(&Ksum[(b * NH + (t >> 4)) * HD + (t & 15)], ksacc);
}

// ---------------------------------------------------------------------------
// Pass B: q = Q@Wq + bq, phi_q; Z = 1/(phi_q . Ksum + eps);
//         V_new = (phi_q @ KV) * Z;  out = V_new @ Wo + bo
// ---------------------------------------------------------------------------
__global__ __launch_bounds__(256) void out_kernel(
    const float* __restrict__ Q,
    const float* __restrict__ Wq, const float* __restrict__ bq,
    const float* __restrict__ Wo, const float* __restrict__ bo,
    const float* __restrict__ KV, const float* __restrict__ Ksum,
    float* __restrict__ out)
{
    __shared__ float Qs[TOK][D];          // 16 KB
    __shared__ float pq[TOK][D];          // 16 KB
    __shared__ float vn[TOK][D];          // 16 KB
    __shared__ float KVs[NH][HD][HD + 1]; // padded: breaks 4-way bank conflict
    __shared__ float Kss[NH][HD];
    __shared__ float Zs[TOK][NH];

    const int b  = blockIdx.x / CHB;
    const int cb = blockIdx.x % CHB;
    const int t  = threadIdx.x;
    const int c  = t & 127;
    const int tg = t >> 7;

    // stage per-batch KV / Ksum once
    for (int i = t; i < NH * HD * HD; i += 256) {
        const int hh = i >> 8, rem = i & 255;
        KVs[hh][rem >> 4][rem & 15] = KV[b * NH * HD * HD + i];
    }
    for (int i = t; i < NH * HD; i += 256)
        Kss[i >> 4][i & 15] = Ksum[b * NH * HD + i];

    const float bqc = bq[c];
    const float boc = bo[c];

    for (int ch = 0; ch < NCHUNK; ++ch) {
        const long tok0 = (long)b * SEQ + (long)cb * TPB_TOKENS + (long)ch * TOK;

        __syncthreads();  // also covers the KVs/Kss staging on ch==0
        {
            const float4* Qg  = (const float4*)(Q + tok0 * D);
            float4*       Qs4 = (float4*)&Qs[0][0];
            for (int i = t; i < TOK * D / 4; i += 256) Qs4[i] = Qg[i];
        }
        __syncthreads();

        // --- q projection + phi ---
        float acc[16];
#pragma unroll
        for (int tt = 0; tt < 16; ++tt) acc[tt] = bqc;
        for (int kk = 0; kk < D; kk += 4) {
            const float w0 = Wq[(kk + 0) * D + c];
            const float w1 = Wq[(kk + 1) * D + c];
            const float w2 = Wq[(kk + 2) * D + c];
            const float w3 = Wq[(kk + 3) * D + c];
#pragma unroll
            for (int tt = 0; tt < 16; ++tt) {
                const float4 q4 = *(const float4*)&Qs[tg * 16 + tt][kk];
                acc[tt] += q4.x * w0 + q4.y * w1 + q4.z * w2 + q4.w * w3;
            }
        }
#pragma unroll
        for (int tt = 0; tt < 16; ++tt) {
            const float x = acc[tt];
            pq[tg * 16 + tt][c] = (x > 0.f) ? (x + 1.f) : __expf(x);
        }
        __syncthreads();

        // --- Z ---
        {
            const int tok = t >> 3, hh = t & 7;
            float s = EPS_;
#pragma unroll
            for (int d = 0; d < HD; ++d) s += pq[tok][hh * HD + d] * Kss[hh][d];
            Zs[tok][hh] = 1.f / s;
        }
        __syncthreads();

        // --- V_new = (phi_q @ KV) * Z ---
        {
            const int hh = c >> 4, m = c & 15;
#pragma unroll
            for (int tt = 0; tt < 16; ++tt) {
                const int tok = tg * 16 + tt;
                float s = 0.f;
#pragma unroll
                for (int d = 0; d < HD; ++d)
                    s += pq[tok][hh * HD + d] * KVs[hh][d][m];
                vn[tok][c] = s * Zs[tok][hh];
            }
        }
        __syncthreads();

        // --- out = vn @ Wo + bo ---
        float acco[16];
#pragma unroll
        for (int tt = 0; tt < 16; ++tt) acco[tt] = boc;
        for (int kk = 0; kk < D; kk += 4) {
            const float w0 = Wo[(kk + 0) * D + c];
            const float w1 = Wo[(kk + 1) * D + c];
            const float w2 = Wo[(kk + 2) * D + c];
            const float w3 = Wo[(kk + 3) * D + c];
#pragma unroll
            for (int tt = 0; tt < 16; ++tt) {
                const float4 v4 = *(const float4*)&vn[tg * 16 + tt][kk];
                acco[tt] += v4.x * w0 + v4.y * w1 + v4.z * w2 + v4.w * w3;
            }
        }
        float* og = out + tok0 * D;
#pragma unroll
        for (int tt = 0; tt < 16; ++tt)
            og[(tg * 16 + tt) * D + c] = acco[tt];
    }
}

extern "C" void kernel_launch(void* const* d_in, const int* in_sizes, int n_in,
                              void* d_out, int out_size, void* d_ws, size_t ws_size,
                              hipStream_t stream) {
    (void)in_sizes; (void)n_in; (void)out_size; (void)ws_size;
    const float* Q  = (const float*)d_in[0];
    const float* Wq = (const float*)d_in[1];
    const float* bq = (const float*)d_in[2];
    const float* Wk = (const float*)d_in[3];
    const float* bk = (const float*)d_in[4];
    const float* Wv = (const float*)d_in[5];
    const float* bv = (const float*)d_in[6];
    const float* Wo = (const float*)d_in[7];
    const float* bo = (const float*)d_in[8];
    float* out  = (float*)d_out;
    float* KV   = (float*)d_ws;
    float* Ksum = KV + KV_ELEMS;

    hipMemsetAsync(d_ws, 0, (KV_ELEMS + KSUM_ELEMS) * sizeof(float), stream);
    kv_accum_kernel<<<dim3(BS * CHB), dim3(256), 0, stream>>>(Q, Wk, bk, Wv, bv, KV, Ksum);
    out_kernel<<<dim3(BS * CHB), dim3(256), 0, stream>>>(Q, Wq, bq, Wo, bo, KV, Ksum, out);
}

// Round 3
// 182.990 us; speedup vs baseline: 3.3890x; 3.3890x over previous
//
#include <hip/hip_runtime.h>
#include <hip/hip_bf16.h>
#include <cmath>

#define BS 8
#define SEQ 16384
#define D 128
#define NH 8
#define HD 16
#define EPS_ 1e-5f

#define CH 64                 // tokens per chunk
#define NCHK 4                // chunks per block
#define BLK_TOK (CH*NCHK)     // 256 tokens per block
#define BPB (SEQ/BLK_TOK)     // 64 blocks per batch
#define NBLK (BS*BPB)         // 512 blocks

typedef __attribute__((ext_vector_type(8))) short bf16x8;
typedef __attribute__((ext_vector_type(4))) float f32x4;
typedef __attribute__((ext_vector_type(4))) unsigned int u32x4;
typedef __attribute__((ext_vector_type(2))) unsigned int u32x2;

#define MFMA16(a,b,c) __builtin_amdgcn_mfma_f32_16x16x32_bf16(a,b,c,0,0,0)

__device__ __forceinline__ unsigned short bf16rn(float x){
    union { __hip_bfloat16 h; unsigned short u; } v;
    v.h = __float2bfloat16(x);
    return v.u;
}
__device__ __forceinline__ float bf16tof(short u){
    union { unsigned int u; float f; } v;
    v.u = ((unsigned int)(unsigned short)u) << 16;
    return v.f;
}
__device__ __forceinline__ unsigned int cvt2(float a, float b){
    union { __hip_bfloat162 h; unsigned int u; } v;
    v.h = __float22bfloat162_rn(make_float2(a, b));
    return v.u;
}
// natural [64 tok][128 col] bf16 LDS; XOR-swizzle, 16B granule (8 shorts)
__device__ __forceinline__ int swzQ(int tok, int col){ return (tok*128 + col) ^ ((tok&7)<<3); }
// transposed [256 col][64 tok] bf16 LDS
__device__ __forceinline__ int swzT(int col, int tok){ return (col*64 + tok) ^ ((col&7)<<3); }

// ---------------------------------------------------------------------------
// Weight pre-pack: bf16 MFMA fragments in ws.
//  WB  (pass A, B-operand, concat [k|v]): [16 nt][4 kt][64 lane][8]
//       elem j = W[k = kt*32+(l>>4)*8+j][n = nt*16+(l&15)]  (W = Wk for nt<8 else Wv)
//  WqA / WoA (pass B, A-operand, transposed): [8 mt][4 kt][64][8]
//       elem j = W[k = kt*32+(l>>4)*8+j][m = mt*16+(l&15)]
// ---------------------------------------------------------------------------
__global__ __launch_bounds__(256) void packW(
    const float* __restrict__ Wk, const float* __restrict__ Wv,
    const float* __restrict__ Wq, const float* __restrict__ Wo,
    short* __restrict__ WB, short* __restrict__ WqA, short* __restrict__ WoA)
{
    int e = blockIdx.x * 256 + threadIdx.x;     // 0..8191
    short v8[8];
    if (e < 4096) {
        int nt = e >> 8, kt = (e >> 6) & 3, l = e & 63;
        int col = nt * 16 + (l & 15);
        const float* W = (col < 128) ? Wk : Wv;
        int cc = col & 127;
#pragma unroll
        for (int j = 0; j < 8; ++j) {
            int k = kt*32 + ((l>>4))*8 + j;
            v8[j] = (short)bf16rn(W[k*D + cc]);
        }
        union { u32x4 u; } p;
        p.u = u32x4{ (unsigned)(unsigned short)v8[0] | ((unsigned)(unsigned short)v8[1]<<16),
                     (unsigned)(unsigned short)v8[2] | ((unsigned)(unsigned short)v8[3]<<16),
                     (unsigned)(unsigned short)v8[4] | ((unsigned)(unsigned short)v8[5]<<16),
                     (unsigned)(unsigned short)v8[6] | ((unsigned)(unsigned short)v8[7]<<16) };
        *(u32x4*)&WB[((nt*4 + kt)*64 + l)*8] = p.u;
    } else {
        int e2 = e - 4096;
        const float* W = (e2 < 2048) ? Wq : Wo;
        short* dst = (e2 < 2048) ? WqA : WoA;
        e2 &= 2047;
        int mt = e2 >> 8, kt = (e2 >> 6) & 3, l = e2 & 63;
        int m = mt*16 + (l & 15);
#pragma unroll
        for (int j = 0; j < 8; ++j) {
            int k = kt*32 + (l>>4)*8 + j;
            v8[j] = (short)bf16rn(W[k*D + m]);
        }
        union { u32x4 u; } p;
        p.u = u32x4{ (unsigned)(unsigned short)v8[0] | ((unsigned)(unsigned short)v8[1]<<16),
                     (unsigned)(unsigned short)v8[2] | ((unsigned)(unsigned short)v8[3]<<16),
                     (unsigned)(unsigned short)v8[4] | ((unsigned)(unsigned short)v8[5]<<16),
                     (unsigned)(unsigned short)v8[6] | ((unsigned)(unsigned short)v8[7]<<16) };
        *(u32x4*)&dst[((mt*4 + kt)*64 + l)*8] = p.u;
    }
}

// ---------------------------------------------------------------------------
// Pass A: k,v projections (MFMA) + phi_k; KV & Ksum via MFMA over tokens.
// ---------------------------------------------------------------------------
__global__ __launch_bounds__(256) void passA(
    const float* __restrict__ Q,
    const float* __restrict__ bk, const float* __restrict__ bv,
    const short* __restrict__ WB,
    float* __restrict__ KV, float* __restrict__ Ksum)
{
    __shared__ __align__(16) short Qlds[64*128];   // 16 KB bf16, natural, swizzled
    __shared__ __align__(16) short TL[256*64];     // 32 KB: [kcol 0..127 | vcol 128..255][tok]

    const int t = threadIdx.x;
    const int w = t >> 6, l = t & 63;
    const int b  = blockIdx.x / BPB;
    const int bb = blockIdx.x % BPB;
    const long base = (long)b * SEQ + (long)bb * BLK_TOK;

    // weight B-frags: wave owns concat cols [w*64, w*64+64) -> nt = w*4+ntl
    bf16x8 wb[4][4];
#pragma unroll
    for (int ntl = 0; ntl < 4; ++ntl)
#pragma unroll
        for (int kt = 0; kt < 4; ++kt)
            wb[ntl][kt] = *(const bf16x8*)&WB[(((w*4+ntl)*4 + kt)*64 + l)*8];

    float bias[4];
#pragma unroll
    for (int ntl = 0; ntl < 4; ++ntl) {
        int col = (w*4+ntl)*16 + (l & 15);
        bias[ntl] = (col < 128) ? bk[col] : bv[col-128];
    }

    // ones B-frag for Ksum (col 0 only)
    union { u32x4 u; bf16x8 h; } onesu;
    unsigned ov = ((l & 15) == 0) ? 0x3F803F80u : 0u;
    onesu.u = u32x4{ov, ov, ov, ov};
    const bf16x8 bones = onesu.h;

    const int h0 = w * 2;
    const f32x4 z4 = {0.f, 0.f, 0.f, 0.f};
    f32x4 kvacc[2] = {z4, z4};
    f32x4 ksacc[2] = {z4, z4};

    for (int c = 0; c < NCHK; ++c) {
        const long tok0 = base + (long)c * CH;

        // --- stage Q chunk -> bf16 LDS (swizzled) ---
#pragma unroll
        for (int i = 0; i < 4; ++i) {
            int lin = i*256 + t;            // 0..1023
            int row = lin >> 4;             // 0..63
            int c0  = (lin & 15) * 8;       // multiple of 8
            const float4* gp = (const float4*)&Q[(tok0 + row)*D + c0];
            float4 a = gp[0], d4 = gp[1];
            union { u32x4 u; } p;
            p.u = u32x4{cvt2(a.x,a.y), cvt2(a.z,a.w), cvt2(d4.x,d4.y), cvt2(d4.z,d4.w)};
            *(u32x4*)&Qlds[swzQ(row, c0)] = p.u;
        }
        __syncthreads();

        // --- k|v projection, non-swapped: C[tok][outcol] ---
        f32x4 acc[4][4];
#pragma unroll
        for (int mt = 0; mt < 4; ++mt)
#pragma unroll
            for (int ntl = 0; ntl < 4; ++ntl)
                acc[mt][ntl] = f32x4{bias[ntl], bias[ntl], bias[ntl], bias[ntl]};
#pragma unroll
        for (int mt = 0; mt < 4; ++mt) {
            bf16x8 af[4];
#pragma unroll
            for (int kt = 0; kt < 4; ++kt)
                af[kt] = *(bf16x8*)&Qlds[swzQ(mt*16 + (l&15), kt*32 + (l>>4)*8)];
#pragma unroll
            for (int ntl = 0; ntl < 4; ++ntl)
#pragma unroll
                for (int kt = 0; kt < 4; ++kt)
                    acc[mt][ntl] = MFMA16(af[kt], wb[ntl][kt], acc[mt][ntl]);
        }

        // --- phi (k-cols) + write transposed TL[col][tok] ---
#pragma unroll
        for (int mt = 0; mt < 4; ++mt)
#pragma unroll
            for (int ntl = 0; ntl < 4; ++ntl) {
                int colg = (w*4+ntl)*16 + (l & 15);
                f32x4 vv = acc[mt][ntl];
                if (colg < 128) {           // wave-uniform branch
#pragma unroll
                    for (int r = 0; r < 4; ++r)
                        vv[r] = (vv[r] > 0.f) ? (vv[r] + 1.f) : __expf(vv[r]);
                }
                int tokb = mt*16 + (l>>4)*4;      // 4 consecutive tokens
                union { u32x2 u; } p;
                p.u = u32x2{cvt2(vv[0], vv[1]), cvt2(vv[2], vv[3])};
                *(u32x2*)&TL[swzT(colg, tokb)] = p.u;
            }
        __syncthreads();

        // --- KV & Ksum MFMA (2 heads per wave) ---
#pragma unroll
        for (int hh = 0; hh < 2; ++hh) {
            int h = h0 + hh;
#pragma unroll
            for (int k2 = 0; k2 < 2; ++k2) {
                bf16x8 afk = *(bf16x8*)&TL[swzT(h*16 + (l&15),       k2*32 + (l>>4)*8)];
                bf16x8 bfv = *(bf16x8*)&TL[swzT(128 + h*16 + (l&15), k2*32 + (l>>4)*8)];
                kvacc[hh] = MFMA16(afk, bfv,  kvacc[hh]);
                ksacc[hh] = MFMA16(afk, bones, ksacc[hh]);
            }
        }
    }

#pragma unroll
    for (int hh = 0; hh < 2; ++hh) {
        int h = h0 + hh;
#pragma unroll
        for (int r = 0; r < 4; ++r) {
            int d = (l>>4)*4 + r, m = l & 15;
            atomicAdd(&KV[((b*NH + h)*HD + d)*HD + m], kvacc[hh][r]);
        }
        if ((l & 15) == 0) {
#pragma unroll
            for (int r = 0; r < 4; ++r)
                atomicAdd(&Ksum[(b*NH + h)*HD + (l>>4)*4 + r], ksacc[hh][r]);
        }
    }
}

// ---------------------------------------------------------------------------
// Pass B: q proj (swapped MFMA), Z (fp32 VALU), V_new (swapped MFMA, hi/lo KV),
//         out proj (swapped MFMA) -> float4 global stores.
// ---------------------------------------------------------------------------
__global__ __launch_bounds__(256) void passB(
    const float* __restrict__ Q,
    const float* __restrict__ bq, const float* __restrict__ bo,
    const short* __restrict__ WqA, const short* __restrict__ WoA,
    const float* __restrict__ KV, const float* __restrict__ Ksum,
    float* __restrict__ out)
{
    __shared__ __align__(16) short Qlds[64*128];
    __shared__ __align__(16) short Pq[64*128];
    __shared__ __align__(16) short Vn[64*128];
    __shared__ float Kss[128];
    __shared__ float Zs[64*8];

    const int t = threadIdx.x;
    const int w = t >> 6, l = t & 63;
    const int b  = blockIdx.x / BPB;
    const int bb = blockIdx.x % BPB;
    const long base = (long)b * SEQ + (long)bb * BLK_TOK;
    const int h0 = w * 2;

    bf16x8 wq[2][4], wo[2][4];
#pragma unroll
    for (int m = 0; m < 2; ++m)
#pragma unroll
        for (int kt = 0; kt < 4; ++kt) {
            wq[m][kt] = *(const bf16x8*)&WqA[(((w*2+m)*4 + kt)*64 + l)*8];
            wo[m][kt] = *(const bf16x8*)&WoA[(((w*2+m)*4 + kt)*64 + l)*8];
        }
    float bqv[2][4], bov[2][4];
#pragma unroll
    for (int m = 0; m < 2; ++m)
#pragma unroll
        for (int r = 0; r < 4; ++r) {
            int cc = (w*2+m)*16 + (l>>4)*4 + r;
            bqv[m][r] = bq[cc];
            bov[m][r] = bo[cc];
        }

    // KV^T hi/lo A-frags for this wave's 2 heads (lanes < 32 hold k=d<16)
    bf16x8 kvhi[2], kvlo[2];
#pragma unroll
    for (int hh = 0; hh < 2; ++hh) {
        union { u32x4 u; bf16x8 h; } phi_, plo_;
        phi_.u = u32x4{0,0,0,0}; plo_.u = u32x4{0,0,0,0};
        if (l < 32) {
            unsigned hiw[8], low[8];
#pragma unroll
            for (int j = 0; j < 8; ++j) {
                int d = (l>>4)*8 + j, m = l & 15;
                float x = KV[((b*NH + h0+hh)*HD + d)*HD + m];
                unsigned short hs = bf16rn(x);
                unsigned short ls = bf16rn(x - bf16tof((short)hs));
                hiw[j] = hs; low[j] = ls;
            }
            phi_.u = u32x4{hiw[0]|(hiw[1]<<16), hiw[2]|(hiw[3]<<16), hiw[4]|(hiw[5]<<16), hiw[6]|(hiw[7]<<16)};
            plo_.u = u32x4{low[0]|(low[1]<<16), low[2]|(low[3]<<16), low[4]|(low[5]<<16), low[6]|(low[7]<<16)};
        }
        kvhi[hh] = phi_.h; kvlo[hh] = plo_.h;
    }
    if (t < 128) Kss[t] = Ksum[b*NH*HD + t];

    for (int c = 0; c < NCHK; ++c) {
        const long tok0 = base + (long)c * CH;

        // --- stage Q ---
#pragma unroll
        for (int i = 0; i < 4; ++i) {
            int lin = i*256 + t;
            int row = lin >> 4;
            int c0  = (lin & 15) * 8;
            const float4* gp = (const float4*)&Q[(tok0 + row)*D + c0];
            float4 a = gp[0], d4 = gp[1];
            union { u32x4 u; } p;
            p.u = u32x4{cvt2(a.x,a.y), cvt2(a.z,a.w), cvt2(d4.x,d4.y), cvt2(d4.z,d4.w)};
            *(u32x4*)&Qlds[swzQ(row, c0)] = p.u;
        }
        __syncthreads();                       // bar1: Qlds ready (also Kss on c==0)

        // --- q-projection, swapped: C[qcol][tok] ---
        f32x4 qa[2][4];
#pragma unroll
        for (int m = 0; m < 2; ++m)
#pragma unroll
            for (int nt = 0; nt < 4; ++nt)
                qa[m][nt] = f32x4{bqv[m][0], bqv[m][1], bqv[m][2], bqv[m][3]};
#pragma unroll
        for (int nt = 0; nt < 4; ++nt) {
            bf16x8 qf[4];
#pragma unroll
            for (int kt = 0; kt < 4; ++kt)
                qf[kt] = *(bf16x8*)&Qlds[swzQ(nt*16 + (l&15), kt*32 + (l>>4)*8)];
#pragma unroll
            for (int m = 0; m < 2; ++m)
#pragma unroll
                for (int kt = 0; kt < 4; ++kt)
                    qa[m][nt] = MFMA16(wq[m][kt], qf[kt], qa[m][nt]);
        }
        // phi + write Pq natural [tok][qcol]
#pragma unroll
        for (int m = 0; m < 2; ++m)
#pragma unroll
            for (int nt = 0; nt < 4; ++nt) {
                f32x4 vv = qa[m][nt];
#pragma unroll
                for (int r = 0; r < 4; ++r)
                    vv[r] = (vv[r] > 0.f) ? (vv[r] + 1.f) : __expf(vv[r]);
                int tok = nt*16 + (l & 15);
                int qc  = (w*2+m)*16 + (l>>4)*4;
                union { u32x2 u; } p;
                p.u = u32x2{cvt2(vv[0], vv[1]), cvt2(vv[2], vv[3])};
                *(u32x2*)&Pq[swzQ(tok, qc)] = p.u;
            }
        __syncthreads();                       // bar2: Pq ready

        // --- Z on fp32 VALU: thread -> (tok = t&63, heads (t>>6)*2+{0,1}) ---
        {
            int tok = t & 63;
#pragma unroll
            for (int hh = 0; hh < 2; ++hh) {
                int h = (t>>6)*2 + hh;
                bf16x8 p0 = *(bf16x8*)&Pq[swzQ(tok, h*16)];
                bf16x8 p1 = *(bf16x8*)&Pq[swzQ(tok, h*16 + 8)];
                float s = EPS_;
#pragma unroll
                for (int j = 0; j < 8; ++j) {
                    s += bf16tof(p0[j]) * Kss[h*16 + j];
                    s += bf16tof(p1[j]) * Kss[h*16 + 8 + j];
                }
                Zs[tok*8 + h] = 1.f / s;
            }
        }

        // --- V_new, swapped per head: C[vcol][tok] ---
        f32x4 vnacc[2][4];
        {
            const f32x4 z4 = {0.f,0.f,0.f,0.f};
#pragma unroll
            for (int hh = 0; hh < 2; ++hh)
#pragma unroll
                for (int nt = 0; nt < 4; ++nt) vnacc[hh][nt] = z4;
        }
#pragma unroll
        for (int hh = 0; hh < 2; ++hh) {
            int h = h0 + hh;
#pragma unroll
            for (int nt = 0; nt < 4; ++nt) {
                union { u32x4 u; bf16x8 h8; } pf; pf.u = u32x4{0,0,0,0};
                if (l < 32)
                    pf.h8 = *(bf16x8*)&Pq[swzQ(nt*16 + (l&15), h*16 + (l>>4)*8)];
                vnacc[hh][nt] = MFMA16(kvhi[hh], pf.h8, vnacc[hh][nt]);
                vnacc[hh][nt] = MFMA16(kvlo[hh], pf.h8, vnacc[hh][nt]);
            }
        }
        __syncthreads();                       // bar3: Zs ready, Pq reads done

        // --- scale by Z, write Vn natural [tok][vcol] ---
#pragma unroll
        for (int hh = 0; hh < 2; ++hh)
#pragma unroll
            for (int nt = 0; nt < 4; ++nt) {
                int tok = nt*16 + (l & 15);
                float z = Zs[tok*8 + (h0+hh)];
                f32x4 vv = vnacc[hh][nt];
                vv[0] *= z; vv[1] *= z; vv[2] *= z; vv[3] *= z;
                int vc = (h0+hh)*16 + (l>>4)*4;
                union { u32x2 u; } p;
                p.u = u32x2{cvt2(vv[0], vv[1]), cvt2(vv[2], vv[3])};
                *(u32x2*)&Vn[swzQ(tok, vc)] = p.u;
            }
        __syncthreads();                       // bar4: Vn ready

        // --- out-projection, swapped: C[outcol][tok] -> global float4 ---
#pragma unroll
        for (int nt = 0; nt < 4; ++nt) {
            bf16x8 vf[4];
#pragma unroll
            for (int kt = 0; kt < 4; ++kt)
                vf[kt] = *(bf16x8*)&Vn[swzQ(nt*16 + (l&15), kt*32 + (l>>4)*8)];
#pragma unroll
            for (int m = 0; m < 2; ++m) {
                f32x4 oa = f32x4{bov[m][0], bov[m][1], bov[m][2], bov[m][3]};
#pragma unroll
                for (int kt = 0; kt < 4; ++kt)
                    oa = MFMA16(wo[m][kt], vf[kt], oa);
                int tok = nt*16 + (l & 15);
                int oc  = (w*2+m)*16 + (l>>4)*4;
                *(float4*)&out[(tok0 + tok)*D + oc] = float4{oa[0], oa[1], oa[2], oa[3]};
            }
        }
    }
}

extern "C" void kernel_launch(void* const* d_in, const int* in_sizes, int n_in,
                              void* d_out, int out_size, void* d_ws, size_t ws_size,
                              hipStream_t stream) {
    (void)in_sizes; (void)n_in; (void)out_size; (void)ws_size;
    const float* Q  = (const float*)d_in[0];
    const float* Wq = (const float*)d_in[1];
    const float* bq = (const float*)d_in[2];
    const float* Wk = (const float*)d_in[3];
    const float* bk = (const float*)d_in[4];
    const float* Wv = (const float*)d_in[5];
    const float* bv = (const float*)d_in[6];
    const float* Wo = (const float*)d_in[7];
    const float* bo = (const float*)d_in[8];
    float* out = (float*)d_out;

    float* KV   = (float*)d_ws;          // 16384 f32
    float* Ksum = KV + 16384;            // 1024 f32
    short* WB   = (short*)(Ksum + 1024); // 32768 bf16
    short* WqA  = WB + 32768;            // 16384 bf16
    short* WoA  = WqA + 16384;           // 16384 bf16

    hipMemsetAsync(d_ws, 0, (16384 + 1024)*sizeof(float), stream);
    packW<<<dim3(32),  dim3(256), 0, stream>>>(Wk, Wv, Wq, Wo, WB, WqA, WoA);
    passA<<<dim3(NBLK), dim3(256), 0, stream>>>(Q, bk, bv, WB, KV, Ksum);
    passB<<<dim3(NBLK), dim3(256), 0, stream>>>(Q, bq, bo, WqA, WoA, KV, Ksum, out);
}